// Round 9
// baseline (43.226 us; speedup 1.0000x reference)
//
#include <hip/hip_runtime.h>

// out[z, k] = sum_{n in segment(k)} vals[n] * x1[z, i_idx[n]] * x2[z, j_idx[n]]
//
// Structure facts (verified over R3-R8):
//  * every output row k is ONE contiguous run in n (runs NOT ascending in k;
//    per-k seg_start/seg_end required; row_ptr CSR is wrong — R4 failure)
//  * every k appears => boundary detection fully populates bounds
//
// R9: scalar-store fix. All R3-R8 variants stored 4B/lane (global_store_dword,
// 256B/wave-instr) and all measured ~26us = 83MB @ 3.3 TB/s — half the 6.5
// TB/s the harness fills reach with 16B/lane. G13: 4B/lane is below the
// 8-16B/lane sweet spot. Fix: thread owns KQ=4 CONSECUTIVE k x ZPT=8 z,
// stores 8x float4 (16B/lane, 1KB/wave-instr, 4x fewer store instrs).
// Four per-k segment loops are compile-time unrolled (acc indices static).

#define ZPT 8
#define KQ 4
#define BLK 256
#define DIM_IN 144
#define NQ (DIM_IN / 4)     // 36 float4 per row
#define STRIDE 12           // dwords; mult of 4 -> b128-aligned; i*12 mod 32
                            // cycles through all 8 quad-bank groups

__global__ void prep_kernel(const int* __restrict__ k_idx,
                            const float* __restrict__ vals,
                            const int* __restrict__ i_idx,
                            const int* __restrict__ j_idx,
                            int nnz,
                            int* __restrict__ seg_start,
                            int* __restrict__ seg_end,
                            int2* __restrict__ packed) {
    int n = blockIdx.x * blockDim.x + threadIdx.x;
    if (n >= nnz) return;
    int k = k_idx[n];
    if (n == 0 || k_idx[n - 1] != k) seg_start[k] = n;
    if (n == nnz - 1 || k_idx[n + 1] != k) seg_end[k] = n + 1;
    packed[n] = make_int2(i_idx[n] | (j_idx[n] << 16), __float_as_int(vals[n]));
}

__global__ __launch_bounds__(BLK) void tp_kernel(
        const float* __restrict__ x1,
        const float* __restrict__ x2,
        const int2* __restrict__ packed,
        const int* __restrict__ seg_start,
        const int* __restrict__ seg_end,
        float* __restrict__ out,
        int dim_out) {
    __shared__ __align__(16) float x1s[DIM_IN * STRIDE];
    __shared__ __align__(16) float x2s[DIM_IN * STRIDE];

    const int tid = threadIdx.x;
    const int z0  = blockIdx.y * ZPT;
    const int k0  = (blockIdx.x * BLK + tid) * KQ;
    const bool live = (k0 < dim_out);   // dim_out % 4 == 0 => whole quad valid

    // ---- stage transposed: x?s[i*STRIDE + t] = x?[(z0+t)*DIM_IN + i] ----
    for (int idx = tid; idx < ZPT * NQ; idx += BLK) {
        const int t  = idx / NQ;
        const int i4 = idx % NQ;
        const float4 a = *(const float4*)(x1 + (size_t)(z0 + t) * DIM_IN + i4 * 4);
        const float4 b = *(const float4*)(x2 + (size_t)(z0 + t) * DIM_IN + i4 * 4);
        const int base = i4 * 4 * STRIDE + t;
        x1s[base             ] = a.x;
        x1s[base +     STRIDE] = a.y;
        x1s[base + 2 * STRIDE] = a.z;
        x1s[base + 3 * STRIDE] = a.w;
        x2s[base             ] = b.x;
        x2s[base +     STRIDE] = b.y;
        x2s[base + 2 * STRIDE] = b.z;
        x2s[base + 3 * STRIDE] = b.w;
    }

    // bounds loads (L2-resident) overlap staging latency
    int s[KQ], e[KQ];
    if (live) {
#pragma unroll
        for (int kk = 0; kk < KQ; ++kk) {
            s[kk] = seg_start[k0 + kk];
            e[kk] = seg_end[k0 + kk];
        }
    }
    __syncthreads();

    if (!live) return;

    float acc[KQ][ZPT];
#pragma unroll
    for (int kk = 0; kk < KQ; ++kk)
#pragma unroll
        for (int t = 0; t < ZPT; ++t) acc[kk][t] = 0.0f;

    // ---- four segment loops, compile-time kk (static acc indexing) ----
#pragma unroll
    for (int kk = 0; kk < KQ; ++kk) {
        int n = s[kk];
        const int en = e[kk];
        if (n < en) {
            int2 ev = packed[n];
            for (;;) {
                const bool more = (n + 1 < en);
                int2 evn;
                if (more) evn = packed[n + 1];

                const float c = __int_as_float(ev.y);
                const int i = ev.x & 0xffff;
                const int j = ev.x >> 16;
                const float4* p1 = (const float4*)(x1s + i * STRIDE);
                const float4* p2 = (const float4*)(x2s + j * STRIDE);
                const float4 a0 = p1[0], a1 = p1[1];
                const float4 b0 = p2[0], b1 = p2[1];
                acc[kk][0] += c * a0.x * b0.x;
                acc[kk][1] += c * a0.y * b0.y;
                acc[kk][2] += c * a0.z * b0.z;
                acc[kk][3] += c * a0.w * b0.w;
                acc[kk][4] += c * a1.x * b1.x;
                acc[kk][5] += c * a1.y * b1.y;
                acc[kk][6] += c * a1.z * b1.z;
                acc[kk][7] += c * a1.w * b1.w;

                ++n;
                if (!more) break;
                ev = evn;
            }
        }
    }

    // ---- vectorized stores: 16B/lane, 1KB/wave-instr, lanes contiguous ----
#pragma unroll
    for (int t = 0; t < ZPT; ++t) {
        float4 v = make_float4(acc[0][t], acc[1][t], acc[2][t], acc[3][t]);
        *(float4*)(out + (size_t)(z0 + t) * dim_out + k0) = v;
    }
}

extern "C" void kernel_launch(void* const* d_in, const int* in_sizes, int n_in,
                              void* d_out, int out_size, void* d_ws, size_t ws_size,
                              hipStream_t stream) {
    const float* x1   = (const float*)d_in[0];
    const float* x2   = (const float*)d_in[1];
    const float* vals = (const float*)d_in[2];
    const int*   kidx = (const int*)d_in[3];
    const int*   iidx = (const int*)d_in[4];
    const int*   jidx = (const int*)d_in[5];
    float* out = (float*)d_out;

    const int n_batch = 1024;                  // N_BATCH in the reference
    const int dim_out = out_size / n_batch;    // 20736
    const int nnz     = in_sizes[2];

    // workspace: seg_start[dim_out], seg_end[dim_out], packed int2[nnz]
    int*  seg_start = (int*)d_ws;
    int*  seg_end   = seg_start + dim_out;
    int2* packed    = (int2*)(seg_end + dim_out);   // 8B-aligned

    {
        int grid = (nnz + 255) / 256;
        prep_kernel<<<grid, 256, 0, stream>>>(kidx, vals, iidx, jidx, nnz,
                                              seg_start, seg_end, packed);
    }

    {
        const int kq_total = dim_out / KQ;               // 5184 quads
        dim3 grid((kq_total + BLK - 1) / BLK, n_batch / ZPT);
        tp_kernel<<<grid, BLK, 0, stream>>>(x1, x2, packed,
                                            seg_start, seg_end, out, dim_out);
    }
}